// Round 3
// baseline (714.635 us; speedup 1.0000x reference)
//
#include <hip/hip_runtime.h>

// ---------- helpers ----------
typedef __bf16 bf16x8 __attribute__((ext_vector_type(8)));
typedef float f32x4 __attribute__((ext_vector_type(4)));

__device__ __forceinline__ float bf2f(unsigned short u) {
  union { unsigned int i; float f; } x;
  x.i = ((unsigned int)u) << 16;
  return x.f;
}
__device__ __forceinline__ unsigned short f2bf(float f) {
  union { float f; unsigned int i; } x;
  x.f = f;
  unsigned int u = x.i;
  u += 0x7fffu + ((u >> 16) & 1u);  // RNE
  return (unsigned short)(u >> 16);
}
__device__ __forceinline__ unsigned int fbits(float f) {
  union { float f; unsigned int i; } x; x.f = f; return x.i;
}
// pack two fp32 -> two truncated bf16 in ONE v_perm_b32
__device__ __forceinline__ unsigned int pack_bf16_trunc(float lo, float hi) {
  return __builtin_amdgcn_perm(fbits(hi), fbits(lo), 0x07060302u);
}

// async global->LDS, 16B per lane, LDS dest wave-uniform base (lane auto-offsets by 16B)
__device__ __forceinline__ void load16_to_lds(const void* g, void* l) {
  __builtin_amdgcn_global_load_lds(
      (__attribute__((address_space(1))) void*)const_cast<void*>(g),
      (__attribute__((address_space(3))) void*)l, 16, 0, 0);
}

// ---------- cast fp32 -> bf16 (RNE, vectorized x4) ----------
__global__ __launch_bounds__(256) void cast_f32_to_bf16(const float* __restrict__ src,
                                                        unsigned short* __restrict__ dst,
                                                        int n4) {
  int i = blockIdx.x * 256 + threadIdx.x;
  if (i < n4) {
    float4 f = ((const float4*)src)[i];
    ushort4 o;
    o.x = f2bf(f.x); o.y = f2bf(f.y); o.z = f2bf(f.z); o.w = f2bf(f.w);
    ((ushort4*)dst)[i] = o;
  }
}

// ---------- NT GEMM: C[m][n] = sum_k A[m][k] * B[n][k] ----------
// 128x128 tile, BK=32, 4 waves each own 64x64 (4x4 MFMA 16x16x32 subtiles).
// OPERAND-SWAP: mfma(bfr, af) -> lane ℓ reg r holds C[ℓ&15][(ℓ>>4)*4+r]:
// one row, 4 consecutive cols per reg -> dwordx4/dwordx2 epilogue stores.
// MODE 0: proj     -> bf16 out, full K
// MODE 1: scores   -> bf16 out * scale, skip blocks above diagonal
// MODE 2: PV       -> f32 out, K-loop clipped at causal diagonal (kEnd = 128*(by+1))
template <int MODE>
__global__ __launch_bounds__(256) void gemm_nt(const unsigned short* __restrict__ A, int lda,
                                               const unsigned short* __restrict__ B, int ldb,
                                               void* __restrict__ Cv, int ldc, int K, float scale,
                                               long long sA, long long sB, long long sC) {
  if (MODE == 1 && blockIdx.x > blockIdx.y) return;  // strictly-upper causal blocks: skip
  A += (long long)blockIdx.z * sA;
  B += (long long)blockIdx.z * sB;
  const int rowBase = blockIdx.y * 128;
  const int colBase = blockIdx.x * 128;
  __shared__ unsigned short As[128 * 32];  // 8 KB, row-major [128][32], no pad (global_load_lds)
  __shared__ unsigned short Bs[128 * 32];

  const int tid = threadIdx.x;
  const int wave = tid >> 6;
  const int lane = tid & 63;

  // staging: per wave 2 issues, each covers 16 tile-rows (1024B contiguous LDS)
  const int slot0 = (wave * 2 + 0) * 512;
  const int slot1 = (wave * 2 + 1) * 512;
  const int rS0 = (wave * 2 + 0) * 16 + (lane >> 2);
  const int rS1 = (wave * 2 + 1) * 16 + (lane >> 2);
  const int cS = (lane & 3) * 8;  // 8 bf16 = 16B per lane
  const unsigned short* aG0 = A + (size_t)(rowBase + rS0) * lda + cS;
  const unsigned short* aG1 = A + (size_t)(rowBase + rS1) * lda + cS;
  const unsigned short* bG0 = B + (size_t)(colBase + rS0) * ldb + cS;
  const unsigned short* bG1 = B + (size_t)(colBase + rS1) * ldb + cS;

  // compute: wave (wr,wc) owns 64x64 of C
  const int wr = wave >> 1, wc = wave & 1;
  const int fRow = lane & 15;
  const int fK = (lane >> 4) * 8;

  f32x4 acc[4][4];
#pragma unroll
  for (int i = 0; i < 4; ++i)
#pragma unroll
    for (int j = 0; j < 4; ++j) {
      f32x4 z = {0.f, 0.f, 0.f, 0.f};
      acc[i][j] = z;
    }

  const int kEnd = (MODE == 2) ? (int)(blockIdx.y + 1) * 128 : K;
  for (int k0 = 0; k0 < kEnd; k0 += 32) {
    __syncthreads();  // protect LDS from previous iteration's readers
    load16_to_lds(aG0 + k0, &As[slot0]);
    load16_to_lds(aG1 + k0, &As[slot1]);
    load16_to_lds(bG0 + k0, &Bs[slot0]);
    load16_to_lds(bG1 + k0, &Bs[slot1]);
    __syncthreads();

    bf16x8 af[4], bfr[4];
#pragma unroll
    for (int i = 0; i < 4; ++i)
      af[i] = *(const bf16x8*)&As[(64 * wr + 16 * i + fRow) * 32 + fK];
#pragma unroll
    for (int j = 0; j < 4; ++j)
      bfr[j] = *(const bf16x8*)&Bs[(64 * wc + 16 * j + fRow) * 32 + fK];
#pragma unroll
    for (int i = 0; i < 4; ++i)
#pragma unroll
      for (int j = 0; j < 4; ++j)  // SWAPPED operands -> transposed D fragment layout
        acc[i][j] = __builtin_amdgcn_mfma_f32_16x16x32_bf16(bfr[j], af[i], acc[i][j], 0, 0, 0);
  }

  // epilogue: lane holds C[row = lane&15][cols = (lane>>4)*4 .. +3] per subtile
  const int er = lane & 15;
  const int ec = (lane >> 4) * 4;
  if constexpr (MODE == 2) {
    float* C = (float*)Cv + (long long)blockIdx.z * sC;
#pragma unroll
    for (int i = 0; i < 4; ++i)
#pragma unroll
      for (int j = 0; j < 4; ++j) {
        size_t base = (size_t)(rowBase + 64 * wr + 16 * i + er) * ldc +
                      (size_t)(colBase + 64 * wc + 16 * j + ec);
        *(f32x4*)((float*)C + base) = acc[i][j];  // 16B aligned: col ≡ 0 mod 4
      }
  } else {
    unsigned short* C = (unsigned short*)Cv + (long long)blockIdx.z * sC;
#pragma unroll
    for (int i = 0; i < 4; ++i)
#pragma unroll
      for (int j = 0; j < 4; ++j) {
        f32x4 a = acc[i][j];
        if constexpr (MODE == 1) {
          a[0] *= scale; a[1] *= scale; a[2] *= scale; a[3] *= scale;
        }
        uint2 p;
        p.x = pack_bf16_trunc(a[0], a[1]);
        p.y = pack_bf16_trunc(a[2], a[3]);
        size_t base = (size_t)(rowBase + 64 * wr + 16 * i + er) * ldc +
                      (size_t)(colBase + 64 * wc + 16 * j + ec);
        *(uint2*)(C + base) = p;  // 8B aligned: col ≡ 0 mod 4, 2B elems
      }
  }
}

// ---------- in-place causal softmax over bf16 score rows (ushort8-vectorized) ----------
// Row r: valid j<=r; writes zeros for r < j < 128*(r/128+1) so PV's MFMA over the
// diagonal 128-block adds exact zeros. Cols beyond that are never read by PV.
__global__ __launch_bounds__(256) void softmax_causal(unsigned short* __restrict__ Sc, int S) {
  const int r = blockIdx.x;
  unsigned short* row = Sc + (size_t)blockIdx.y * S * S + (size_t)r * S;
  const int ncols = ((r >> 7) + 1) << 7;  // multiple of 128 -> 16B-divisible
  const int tid = threadIdx.x;
  const int nIt = (ncols + 2047) >> 11;  // ceil(ncols / (256*8)) <= 2

  float v[16];
#pragma unroll
  for (int e = 0; e < 16; ++e) v[e] = -1e30f;  // FIX: all lanes initialized (r2 bug: v[8..15]
                                               // were uninit garbage for rows with nIt==1)
  float m = -1e30f;
#pragma unroll 2
  for (int it = 0; it < nIt; ++it) {
    int j0 = (it << 11) + tid * 8;
    if (j0 < ncols) {
      uint4 u = *(const uint4*)(row + j0);
      const unsigned short* us = (const unsigned short*)&u;
#pragma unroll
      for (int e = 0; e < 8; ++e) {
        float x = bf2f(us[e]);
        x = (j0 + e <= r) ? x : -1e30f;
        v[it * 8 + e] = x;
        m = fmaxf(m, x);
      }
    }
  }
  __shared__ float red[4];
  for (int off = 32; off; off >>= 1) m = fmaxf(m, __shfl_xor(m, off, 64));
  if ((tid & 63) == 0) red[tid >> 6] = m;
  __syncthreads();
  m = fmaxf(fmaxf(red[0], red[1]), fmaxf(red[2], red[3]));
  __syncthreads();

  float s = 0.f;
#pragma unroll
  for (int e = 0; e < 16; ++e) {
    float x = v[e];
    float ex = (x > -1e29f) ? __expf(x - m) : 0.f;
    v[e] = ex;
    s += ex;
  }
  for (int off = 32; off; off >>= 1) s += __shfl_xor(s, off, 64);
  if ((tid & 63) == 0) red[tid >> 6] = s;
  __syncthreads();
  s = red[0] + red[1] + red[2] + red[3];
  float inv = 1.f / s;

#pragma unroll 2
  for (int it = 0; it < nIt; ++it) {
    int j0 = (it << 11) + tid * 8;
    if (j0 < ncols) {
      uint4 o;
      unsigned int* po = (unsigned int*)&o;
#pragma unroll
      for (int e = 0; e < 4; ++e)
        po[e] = pack_bf16_trunc(v[it * 8 + 2 * e] * inv, v[it * 8 + 2 * e + 1] * inv);
      *(uint4*)(row + j0) = o;
    }
  }
}

// ---------- launch ----------
extern "C" void kernel_launch(void* const* d_in, const int* in_sizes, int n_in,
                              void* d_out, int out_size, void* d_ws, size_t ws_size,
                              hipStream_t stream) {
  const float* X  = (const float*)d_in[0];
  const float* Wq = (const float*)d_in[1];
  const float* Wk = (const float*)d_in[2];
  const float* Wv = (const float*)d_in[3];
  float* out = (float*)d_out;

  const int Bsz = 4, S = 4096, D = 1024;
  const long long MD = (long long)Bsz * S;  // 16384 total rows

  // ws layout (bf16): Xb[16384x1024] Wb[3x1024x1024] Qb Kb (each 16384x1024) Vt[1024x16384] Sc[nb x 4096x4096]
  unsigned short* Xb = (unsigned short*)d_ws;
  unsigned short* Wb = Xb + MD * D;
  unsigned short* Qb = Wb + 3LL * D * D;
  unsigned short* Kb = Qb + MD * D;
  unsigned short* Vt = Kb + MD * D;
  unsigned short* Sc = Vt + MD * D;

  size_t fixedB = (size_t)(4 * MD * D + 3LL * D * D) * 2;  // ~140.5 MB
  size_t perB = (size_t)S * S * 2;                         // 33.5 MB per batch of scores
  int nb = 1;
  if (ws_size >= fixedB + 4 * perB) nb = 4;
  else if (ws_size >= fixedB + 2 * perB) nb = 2;

  // 1) casts
  cast_f32_to_bf16<<<dim3((unsigned)(MD * D / 4 / 256)), 256, 0, stream>>>(X, Xb, (int)(MD * D / 4));
  cast_f32_to_bf16<<<dim3((unsigned)((long long)D * D / 4 / 256)), 256, 0, stream>>>(Wq, Wb, D * D / 4);
  cast_f32_to_bf16<<<dim3((unsigned)((long long)D * D / 4 / 256)), 256, 0, stream>>>(Wk, Wb + (long long)D * D, D * D / 4);
  cast_f32_to_bf16<<<dim3((unsigned)((long long)D * D / 4 / 256)), 256, 0, stream>>>(Wv, Wb + 2LL * D * D, D * D / 4);

  // 2) Q,K projections: C[s][e] = X[s,:].W[e,:]  (z picks Wq/Wk -> Qb/Kb)
  gemm_nt<0><<<dim3(D / 128, (unsigned)(MD / 128), 2), 256, 0, stream>>>(
      Xb, D, Wb, D, (void*)Qb, D, D, 1.f, 0LL, (long long)D * D, MD * D);
  // 3) V produced transposed: Vt[e][s] = Wv[e,:].X[s,:]
  gemm_nt<0><<<dim3((unsigned)(MD / 128), D / 128, 1), 256, 0, stream>>>(
      Wb + 2LL * D * D, D, Xb, D, (void*)Vt, (int)MD, D, 1.f, 0LL, 0LL, 0LL);

  // 4) per-batch: scores -> softmax -> PV
  const float sscale = 1.0f / 32.0f;  // 1/sqrt(1024)
  for (int b0 = 0; b0 < Bsz; b0 += nb) {
    gemm_nt<1><<<dim3(S / 128, S / 128, nb), 256, 0, stream>>>(
        Qb + (long long)b0 * S * D, D, Kb + (long long)b0 * S * D, D, (void*)Sc, S, D, sscale,
        (long long)S * D, (long long)S * D, (long long)S * S);
    softmax_causal<<<dim3(S, nb), 256, 0, stream>>>(Sc, S);
    gemm_nt<2><<<dim3(D / 128, S / 128, nb), 256, 0, stream>>>(
        Sc, S, Vt + (long long)b0 * S, (int)MD, (void*)(out + (long long)b0 * S * D), D, S, 1.f,
        (long long)S * S, (long long)S, (long long)S * D);
  }
}

// Round 4
// 565.606 us; speedup vs baseline: 1.2635x; 1.2635x over previous
//
#include <hip/hip_runtime.h>

// ---------- helpers ----------
typedef __bf16 bf16x8 __attribute__((ext_vector_type(8)));
typedef float f32x4 __attribute__((ext_vector_type(4)));

__device__ __forceinline__ float bf2f(unsigned short u) {
  union { unsigned int i; float f; } x;
  x.i = ((unsigned int)u) << 16;
  return x.f;
}
__device__ __forceinline__ unsigned short f2bf(float f) {
  union { float f; unsigned int i; } x;
  x.f = f;
  unsigned int u = x.i;
  u += 0x7fffu + ((u >> 16) & 1u);  // RNE
  return (unsigned short)(u >> 16);
}
__device__ __forceinline__ unsigned int fbits(float f) {
  union { float f; unsigned int i; } x; x.f = f; return x.i;
}
// pack two fp32 -> two truncated bf16 in ONE v_perm_b32
__device__ __forceinline__ unsigned int pack_bf16_trunc(float lo, float hi) {
  return __builtin_amdgcn_perm(fbits(hi), fbits(lo), 0x07060302u);
}

// async global->LDS, 16B per lane, LDS dest wave-uniform base (lane auto-offsets by 16B)
__device__ __forceinline__ void load16_to_lds(const void* g, void* l) {
  __builtin_amdgcn_global_load_lds(
      (__attribute__((address_space(1))) void*)const_cast<void*>(g),
      (__attribute__((address_space(3))) void*)l, 16, 0, 0);
}

// packed lower-triangle score buffer: 528 blocks of 128x128 bf16, block-linear.
// block (by,bx), bx<=by, stored at (by*(by+1)/2 + bx)*16384; elem (r,c) at +r*128+c.
#define TRI_BLK 16384
#define TRI_NBLK 528
#define PER_BATCH_EL (TRI_NBLK * TRI_BLK)  // 8,650,752 el = 17.3 MB

// ---------- cast fp32 -> bf16 (RNE, vectorized x4) ----------
__global__ __launch_bounds__(256) void cast_f32_to_bf16(const float* __restrict__ src,
                                                        unsigned short* __restrict__ dst,
                                                        int n4) {
  int i = blockIdx.x * 256 + threadIdx.x;
  if (i < n4) {
    float4 f = ((const float4*)src)[i];
    ushort4 o;
    o.x = f2bf(f.x); o.y = f2bf(f.y); o.z = f2bf(f.z); o.w = f2bf(f.w);
    ((ushort4*)dst)[i] = o;
  }
}

// ---------- NT GEMM: C[m][n] = sum_k A[m][k] * B[n][k] ----------
// 128x128 tile, BK=32, 4 waves each own 64x64 (4x4 MFMA 16x16x32 subtiles).
// OPERAND-SWAP: mfma(bfr, af) -> lane l reg r holds C[l&15][(l>>4)*4+r]:
// one row, 4 consecutive cols per reg -> dwordx4/dwordx2 epilogue stores.
// MODE 0: proj    -> bf16 out row-major, full K, grid (nx, ny, z)
// MODE 1: scores  -> bf16*scale into PACKED-TRI C, grid (528, 1, nb), tri-decode blockIdx.x
// MODE 2: PV      -> f32 out row-major, A is PACKED-TRI, K clipped at diagonal,
//                    by = 31-blockIdx.y (deepest blocks launch first)
template <int MODE>
__global__ __launch_bounds__(256) void gemm_nt(const unsigned short* __restrict__ A, int lda,
                                               const unsigned short* __restrict__ B, int ldb,
                                               void* __restrict__ Cv, int ldc, int K, float scale,
                                               long long sA, long long sB, long long sC) {
  int by, bx;
  if constexpr (MODE == 1) {
    int b = blockIdx.x;
    by = (int)((__fsqrt_rn(8.f * b + 1.f) - 1.f) * 0.5f);
    while ((by + 1) * (by + 2) / 2 <= b) ++by;
    while (by * (by + 1) / 2 > b) --by;
    bx = b - by * (by + 1) / 2;
  } else if constexpr (MODE == 2) {
    by = (int)gridDim.y - 1 - (int)blockIdx.y;  // deepest K first
    bx = blockIdx.x;
  } else {
    by = blockIdx.y;
    bx = blockIdx.x;
  }
  A += (long long)blockIdx.z * sA;
  B += (long long)blockIdx.z * sB;
  if constexpr (MODE == 2) A += (long long)(by * (by + 1) / 2) * TRI_BLK;  // row-block base

  const int rowBase = by * 128;
  const int colBase = bx * 128;
  __shared__ unsigned short As[128 * 32];  // 8 KB, [128][32] row-major, no pad (global_load_lds)
  __shared__ unsigned short Bs[128 * 32];

  const int tid = threadIdx.x;
  const int wave = tid >> 6;
  const int lane = tid & 63;

  // staging: per wave 2 issues, each covers 16 tile-rows (1024B contiguous LDS)
  const int slot0 = (wave * 2 + 0) * 512;
  const int slot1 = (wave * 2 + 1) * 512;
  const int rS0 = (wave * 2 + 0) * 16 + (lane >> 2);
  const int rS1 = (wave * 2 + 1) * 16 + (lane >> 2);
  const int cS = (lane & 3) * 8;  // 8 bf16 = 16B per lane
  const unsigned short *aG0, *aG1;
  if constexpr (MODE == 2) {  // packed A: row local, col (k>>7)*TRI_BLK + (k&127)
    aG0 = A + rS0 * 128 + cS;
    aG1 = A + rS1 * 128 + cS;
  } else {
    aG0 = A + (size_t)(rowBase + rS0) * lda + cS;
    aG1 = A + (size_t)(rowBase + rS1) * lda + cS;
  }
  const unsigned short* bG0 = B + (size_t)(colBase + rS0) * ldb + cS;
  const unsigned short* bG1 = B + (size_t)(colBase + rS1) * ldb + cS;

  // compute: wave (wr,wc) owns 64x64 of C
  const int wr = wave >> 1, wc = wave & 1;
  const int fRow = lane & 15;
  const int fK = (lane >> 4) * 8;

  f32x4 acc[4][4];
#pragma unroll
  for (int i = 0; i < 4; ++i)
#pragma unroll
    for (int j = 0; j < 4; ++j) {
      f32x4 z = {0.f, 0.f, 0.f, 0.f};
      acc[i][j] = z;
    }

  const int kEnd = (MODE == 2) ? (by + 1) * 128 : K;
  for (int k0 = 0; k0 < kEnd; k0 += 32) {
    __syncthreads();  // protect LDS from previous iteration's readers
    if constexpr (MODE == 2) {
      int aOff = ((k0 >> 7) << 14) + (k0 & 127);
      load16_to_lds(aG0 + aOff, &As[slot0]);
      load16_to_lds(aG1 + aOff, &As[slot1]);
    } else {
      load16_to_lds(aG0 + k0, &As[slot0]);
      load16_to_lds(aG1 + k0, &As[slot1]);
    }
    load16_to_lds(bG0 + k0, &Bs[slot0]);
    load16_to_lds(bG1 + k0, &Bs[slot1]);
    __syncthreads();

    bf16x8 af[4], bfr[4];
#pragma unroll
    for (int i = 0; i < 4; ++i)
      af[i] = *(const bf16x8*)&As[(64 * wr + 16 * i + fRow) * 32 + fK];
#pragma unroll
    for (int j = 0; j < 4; ++j)
      bfr[j] = *(const bf16x8*)&Bs[(64 * wc + 16 * j + fRow) * 32 + fK];
#pragma unroll
    for (int i = 0; i < 4; ++i)
#pragma unroll
      for (int j = 0; j < 4; ++j)  // SWAPPED operands -> transposed D fragment layout
        acc[i][j] = __builtin_amdgcn_mfma_f32_16x16x32_bf16(bfr[j], af[i], acc[i][j], 0, 0, 0);
  }

  // epilogue: lane holds C[row = lane&15][cols = (lane>>4)*4 .. +3] per subtile
  const int er = lane & 15;
  const int ec = (lane >> 4) * 4;
  if constexpr (MODE == 2) {
    float* C = (float*)Cv + (long long)blockIdx.z * sC;
#pragma unroll
    for (int i = 0; i < 4; ++i)
#pragma unroll
      for (int j = 0; j < 4; ++j) {
        size_t base = (size_t)(rowBase + 64 * wr + 16 * i + er) * ldc +
                      (size_t)(colBase + 64 * wc + 16 * j + ec);
        *(f32x4*)((float*)C + base) = acc[i][j];  // 16B aligned: col ≡ 0 mod 4
      }
  } else if constexpr (MODE == 1) {
    unsigned short* C = (unsigned short*)Cv + (long long)blockIdx.z * sC +
                        (size_t)(by * (by + 1) / 2 + bx) * TRI_BLK;
#pragma unroll
    for (int i = 0; i < 4; ++i)
#pragma unroll
      for (int j = 0; j < 4; ++j) {
        f32x4 a = acc[i][j];
        a[0] *= scale; a[1] *= scale; a[2] *= scale; a[3] *= scale;
        uint2 p;
        p.x = pack_bf16_trunc(a[0], a[1]);
        p.y = pack_bf16_trunc(a[2], a[3]);
        int row = 64 * wr + 16 * i + er;
        int col = 64 * wc + 16 * j + ec;
        *(uint2*)(C + row * 128 + col) = p;  // 8B aligned
      }
  } else {
    unsigned short* C = (unsigned short*)Cv + (long long)blockIdx.z * sC;
#pragma unroll
    for (int i = 0; i < 4; ++i)
#pragma unroll
      for (int j = 0; j < 4; ++j) {
        uint2 p;
        p.x = pack_bf16_trunc(acc[i][j][0], acc[i][j][1]);
        p.y = pack_bf16_trunc(acc[i][j][2], acc[i][j][3]);
        size_t base = (size_t)(rowBase + 64 * wr + 16 * i + er) * ldc +
                      (size_t)(colBase + 64 * wc + 16 * j + ec);
        *(uint2*)(C + base) = p;  // 8B aligned
      }
  }
}

// ---------- in-place causal softmax over PACKED-TRI bf16 scores ----------
// Row r lives in blocks (by=r>>7, bx=0..by); 128-col segment bx at
// triBase(by) + bx*TRI_BLK + (r&127)*128. Writes zeros for r<j<128*(by+1).
__global__ __launch_bounds__(256) void softmax_causal(unsigned short* __restrict__ Sc) {
  const int r = blockIdx.x;
  const int by = r >> 7;
  unsigned short* rowB = Sc + (size_t)blockIdx.y * PER_BATCH_EL +
                         (size_t)(by * (by + 1) / 2) * TRI_BLK + (size_t)(r & 127) * 128;
  const int ncols = (by + 1) << 7;  // multiple of 128
  const int tid = threadIdx.x;
  const int nIt = (ncols + 2047) >> 11;  // ceil(ncols / (256*8)) <= 2

  float v[16];
#pragma unroll
  for (int e = 0; e < 16; ++e) v[e] = -1e30f;
  float m = -1e30f;
#pragma unroll 2
  for (int it = 0; it < nIt; ++it) {
    int j0 = (it << 11) + tid * 8;  // 8 | 128 -> chunk stays in one segment
    if (j0 < ncols) {
      uint4 u = *(const uint4*)(rowB + ((j0 >> 7) << 14) + (j0 & 127));
      const unsigned short* us = (const unsigned short*)&u;
#pragma unroll
      for (int e = 0; e < 8; ++e) {
        float x = bf2f(us[e]);
        x = (j0 + e <= r) ? x : -1e30f;
        v[it * 8 + e] = x;
        m = fmaxf(m, x);
      }
    }
  }
  __shared__ float red[4];
  for (int off = 32; off; off >>= 1) m = fmaxf(m, __shfl_xor(m, off, 64));
  if ((tid & 63) == 0) red[tid >> 6] = m;
  __syncthreads();
  m = fmaxf(fmaxf(red[0], red[1]), fmaxf(red[2], red[3]));
  __syncthreads();

  float s = 0.f;
#pragma unroll
  for (int e = 0; e < 16; ++e) {
    float x = v[e];
    float ex = (x > -1e29f) ? __expf(x - m) : 0.f;
    v[e] = ex;
    s += ex;
  }
  for (int off = 32; off; off >>= 1) s += __shfl_xor(s, off, 64);
  if ((tid & 63) == 0) red[tid >> 6] = s;
  __syncthreads();
  s = red[0] + red[1] + red[2] + red[3];
  float inv = 1.f / s;

#pragma unroll 2
  for (int it = 0; it < nIt; ++it) {
    int j0 = (it << 11) + tid * 8;
    if (j0 < ncols) {
      uint4 o;
      unsigned int* po = (unsigned int*)&o;
#pragma unroll
      for (int e = 0; e < 4; ++e)
        po[e] = pack_bf16_trunc(v[it * 8 + 2 * e] * inv, v[it * 8 + 2 * e + 1] * inv);
      *(uint4*)(rowB + ((j0 >> 7) << 14) + (j0 & 127)) = o;
    }
  }
}

// ---------- launch ----------
extern "C" void kernel_launch(void* const* d_in, const int* in_sizes, int n_in,
                              void* d_out, int out_size, void* d_ws, size_t ws_size,
                              hipStream_t stream) {
  const float* X  = (const float*)d_in[0];
  const float* Wq = (const float*)d_in[1];
  const float* Wk = (const float*)d_in[2];
  const float* Wv = (const float*)d_in[3];
  float* out = (float*)d_out;

  const int Bsz = 4, S = 4096, D = 1024;
  const long long MD = (long long)Bsz * S;  // 16384 total rows
  const long long elBig = MD * D;           // 16,777,216

  // ws layout (bf16 el): Wb[3DD] Qb[elBig] Kb[elBig] Vt[elBig] Xb[elBig]...
  // Sc ALIASES Xb (Xb dead after projections; stream order makes reuse safe).
  unsigned short* Wb = (unsigned short*)d_ws;
  unsigned short* Qb = Wb + 3LL * D * D;
  unsigned short* Kb = Qb + elBig;
  unsigned short* Vt = Kb + elBig;
  unsigned short* Xb = Vt + elBig;
  unsigned short* Sc = Xb;  // packed-tri, PER_BATCH_EL per batch

  const long long offXb = 3LL * D * D + 3LL * elBig;
  auto needB = [&](int nb) {
    long long tail = (long long)nb * PER_BATCH_EL;
    if (tail < elBig) tail = elBig;
    return (size_t)((offXb + tail) * 2);
  };
  int nb = 1;
  if (ws_size >= needB(4)) nb = 4;        // 176.2 MB
  else if (ws_size >= needB(2)) nb = 2;   // 141.6 MB

  // 1) casts
  cast_f32_to_bf16<<<dim3((unsigned)(elBig / 4 / 256)), 256, 0, stream>>>(X, Xb, (int)(elBig / 4));
  cast_f32_to_bf16<<<dim3((unsigned)((long long)D * D / 4 / 256)), 256, 0, stream>>>(Wq, Wb, D * D / 4);
  cast_f32_to_bf16<<<dim3((unsigned)((long long)D * D / 4 / 256)), 256, 0, stream>>>(Wk, Wb + (long long)D * D, D * D / 4);
  cast_f32_to_bf16<<<dim3((unsigned)((long long)D * D / 4 / 256)), 256, 0, stream>>>(Wv, Wb + 2LL * D * D, D * D / 4);

  // 2) Q,K projections: C[s][e] = X[s,:].W[e,:]  (z picks Wq/Wk -> Qb/Kb)
  gemm_nt<0><<<dim3(D / 128, (unsigned)(MD / 128), 2), 256, 0, stream>>>(
      Xb, D, Wb, D, (void*)Qb, D, D, 1.f, 0LL, (long long)D * D, elBig);
  // 3) V produced transposed: Vt[e][s] = Wv[e,:].X[s,:]
  gemm_nt<0><<<dim3((unsigned)(MD / 128), D / 128, 1), 256, 0, stream>>>(
      Wb + 2LL * D * D, D, Xb, D, (void*)Vt, (int)MD, D, 1.f, 0LL, 0LL, 0LL);

  // 4) per-batch-group: scores(packed tri) -> softmax -> PV
  const float sscale = 1.0f / 32.0f;  // 1/sqrt(1024)
  for (int b0 = 0; b0 < Bsz; b0 += nb) {
    gemm_nt<1><<<dim3(TRI_NBLK, 1, nb), 256, 0, stream>>>(
        Qb + (long long)b0 * S * D, D, Kb + (long long)b0 * S * D, D, (void*)Sc, 0, D, sscale,
        (long long)S * D, (long long)S * D, (long long)PER_BATCH_EL);
    softmax_causal<<<dim3(S, nb), 256, 0, stream>>>(Sc);
    gemm_nt<2><<<dim3(D / 128, S / 128, nb), 256, 0, stream>>>(
        Sc, 0, Vt + (long long)b0 * S, (int)MD, (void*)(out + (long long)b0 * S * D), D, S, 1.f,
        (long long)PER_BATCH_EL, (long long)S, (long long)S * D);
  }
}